// Round 2
// baseline (254.556 us; speedup 1.0000x reference)
//
#include <hip/hip_runtime.h>

#define SEQ 2048
#define DHEAD 128
#define BK 32
#define NBH 32

typedef __attribute__((ext_vector_type(8))) short bf16x8;
typedef __attribute__((ext_vector_type(4))) short bf16x4;
typedef __attribute__((ext_vector_type(16))) float f32x16;
typedef __attribute__((ext_vector_type(4))) unsigned int u32x4;

__device__ __forceinline__ unsigned short f2bf(float f) {
    unsigned u = __builtin_bit_cast(unsigned, f);
    u += 0x7fffu + ((u >> 16) & 1u);
    return (unsigned short)(u >> 16);
}

__device__ __forceinline__ void gload16(const unsigned short* g, unsigned short* l) {
    __builtin_amdgcn_global_load_lds((const __attribute__((address_space(1))) void*)g,
                                     (__attribute__((address_space(3))) void*)l, 16, 0, 0);
}

// Fused prepass. Blocks 0..1023: K fp32 [bh*128+d][2048] -> bf16 [bh][l][128],
// 16B-chunk XOR-swizzled per row: phys = logical ^ ((l&7) ^ (((l>>3)&3)<<1)).
// The (l>>3) term makes rows 8 apart land in different bank-groups (the old
// l&7-only swizzle was constant across stride-8 lane groups -> 4-way conflict,
// 8.4M conflict cycles measured). Blocks 1024..5119: V fp32 -> bf16
// [bh][kt][dv][32] with kl bits 2<->3 swapped (PV B-frag register order),
// chunk-swizzled phys = logical ^ (((dv>>1)&3) ^ ((dv>>3)&3)).
__global__ __launch_bounds__(256)
void cvt_kernel(const float* __restrict__ kin, const float* __restrict__ vin,
                unsigned short* __restrict__ kout, unsigned short* __restrict__ vout) {
    const int tid = threadIdx.x;
    if (blockIdx.x < 1024) {
        __shared__ unsigned short tileT[DHEAD][66];   // [d][l]
        const int bh = blockIdx.x & 31;
        const int l0 = (blockIdx.x >> 5) * 64;
        const float* ip = kin + (size_t)bh * DHEAD * SEQ;
        unsigned short* opx = kout + ((size_t)bh * SEQ + l0) * DHEAD;
        const int l4 = (tid & 15) * 4;
        const int dq = tid >> 4;
        for (int pass = 0; pass < 8; ++pass) {
            int d = pass * 16 + dq;
            float4 f = *(const float4*)&ip[(size_t)d * SEQ + l0 + l4];
            unsigned lo = (unsigned)f2bf(f.x) | ((unsigned)f2bf(f.y) << 16);
            unsigned hi = (unsigned)f2bf(f.z) | ((unsigned)f2bf(f.w) << 16);
            *(unsigned*)&tileT[d][l4]     = lo;
            *(unsigned*)&tileT[d][l4 + 2] = hi;
        }
        __syncthreads();
        const int lw = tid >> 2;
        const int cw = tid & 3;
        const int ksw = (lw & 7) ^ (((lw >> 3) & 3) << 1);   // row = lw & 31 in-tile
        for (int j = 0; j < 4; ++j) {
            int pc = j * 4 + cw;           // phys chunk
            int lc = pc ^ ksw;             // logical chunk
            unsigned short tmp[8];
            for (int k2 = 0; k2 < 8; ++k2) tmp[k2] = tileT[lc * 8 + k2][lw];
            *(bf16x8*)&opx[(size_t)lw * DHEAD + pc * 8] = *(bf16x8*)tmp;
        }
    } else {
        size_t f = ((size_t)(blockIdx.x - 1024) * 256 + tid) * 8;
        int bh  = (int)(f >> 18);
        int rem = (int)(f & 262143);
        int kt  = rem >> 12;
        int r2  = rem & 4095;
        int dv  = r2 >> 5;
        int e0  = r2 & 31;
        const float* src = vin + ((size_t)bh * DHEAD + dv) * SEQ + kt * BK + e0;
        float4 a = *(const float4*)src;
        float4 b = *(const float4*)(src + 4);
        unsigned short p0[4] = {f2bf(a.x), f2bf(a.y), f2bf(a.z), f2bf(a.w)};
        unsigned short p1[4] = {f2bf(b.x), f2bf(b.y), f2bf(b.z), f2bf(b.w)};
        // kl = 16a + 8b + 4h + t  ->  logical position 16a + 8h + 4b + t
        const int aa = e0 >> 4;
        const int bb = (e0 >> 3) & 1;
        const int w  = ((dv >> 1) & 3) ^ ((dv >> 3) & 3);
        size_t rowb = ((size_t)bh * (SEQ / BK) + kt) * (DHEAD * BK) + (size_t)dv * BK;
        *(bf16x4*)&vout[rowb + (size_t)(((2 * aa) ^ w) * 8 + 4 * bb)]     = *(bf16x4*)p0;
        *(bf16x4*)&vout[rowb + (size_t)(((2 * aa + 1) ^ w) * 8 + 4 * bb)] = *(bf16x4*)p1;
    }
}

// 32x32x16 swapped-operand attention, 64 queries per wave (nQ=2).
// Diagnosis from round 1: attn is LDS-read-BW bound (every wave reads the
// full 16KB K+V tile for only 32 queries; 8 conflict-cyc per b128 read).
// Fix: each wave now serves TWO 32-query sets from the SAME 16 ds_reads per
// tile (LDS read volume halves per MFMA), and the swizzles gain a (row>>3)
// term so stride-8 lane groups are conflict-free. 128-thread blocks, grid
// 512 -> 2 blocks/CU, 4 waves/CU (1/SIMD): VGPR ~250 costs no occupancy.
__global__ __launch_bounds__(128, 1)
void attn_main(const float* __restrict__ q,
               const unsigned short* __restrict__ kTg,
               const unsigned short* __restrict__ vW,
               const float* __restrict__ gamma,
               float* __restrict__ out) {
    __shared__ __attribute__((aligned(16))) unsigned short kS[2][BK * DHEAD];  // [l][d] swizzled
    __shared__ __attribute__((aligned(16))) unsigned short vS[2][DHEAD * BK];  // [dv][kl-perm] swizzled

    const int tid  = threadIdx.x;        // 0..127
    const int wv   = tid >> 6;           // 0..1
    const int lane = tid & 63;
    const int c5   = lane & 31;
    const int hi   = lane >> 5;

    const int bh  = blockIdx.x & 31;     // same-head blocks stride 32 -> same XCD
    const int qlb = blockIdx.x >> 5;     // 0..15
    const size_t base = (size_t)bh * SEQ * DHEAD;

    const float* qp = q + base;              // fp32 [d][2048]
    const unsigned short* kb = kTg + base;   // [l][128] swizzled
    const unsigned short* vb = vW + base;    // [kt][dv][32] permuted+swizzled
    float* op = out + base;                  // [dv][2048]

    const int ql0 = qlb * 128 + wv * 64;     // this wave's 64 queries
    const float SCL = 0.08838834764831845f * 1.44269504088896340f; // 1/sqrt(128)*log2e

    // prime tile 0 into buffer 0 (DMA flies while Q frags load below)
#pragma unroll
    for (int i = 0; i < 4; ++i) {
        gload16(kb + (size_t)(tid + i * 128) * 8, &kS[0][(tid + i * 128) * 8]);
        gload16(vb + (size_t)(tid + i * 128) * 8, &vS[0][(tid + i * 128) * 8]);
    }

    // Q B-frags for both query sets: B[n=ql][k=hi*8+j], d = s*16 + hi*8 + j
    bf16x8 qf0[8], qf1[8];
#pragma unroll
    for (int s = 0; s < 8; ++s) {
        bf16x8 t0, t1;
#pragma unroll
        for (int j = 0; j < 8; ++j) {
            const size_t drow = (size_t)(s * 16 + hi * 8 + j) * SEQ;
            t0[j] = (short)f2bf(qp[drow + ql0 + c5] * SCL);
            t1[j] = (short)f2bf(qp[drow + ql0 + 32 + c5] * SCL);
        }
        qf0[s] = t0;
        qf1[s] = t1;
    }

    f32x16 acc0[4], acc1[4];
#pragma unroll
    for (int t = 0; t < 4; ++t)
#pragma unroll
        for (int i = 0; i < 16; ++i) { acc0[t][i] = 0.f; acc1[t][i] = 0.f; }
    float lp0 = 0.f, lp1 = 0.f;

    const int ksw = (c5 & 7) ^ (((c5 >> 3) & 3) << 1);
    const int vsw = ((c5 >> 1) & 3) ^ ((c5 >> 3) & 3);

    for (int kt = 0; kt < SEQ / BK; ++kt) {
        const int cur = kt & 1;
        __syncthreads();   // buf[cur] landed (prefetch flew during previous compute)

        if (kt + 1 < SEQ / BK) {   // prefetch next tile into buf[cur^1]
            const unsigned short* kg = kb + (size_t)(kt + 1) * (BK * DHEAD);
            const unsigned short* vg = vb + (size_t)(kt + 1) * (DHEAD * BK);
#pragma unroll
            for (int i = 0; i < 4; ++i) {
                gload16(kg + (size_t)(tid + i * 128) * 8, &kS[cur ^ 1][(tid + i * 128) * 8]);
                gload16(vg + (size_t)(tid + i * 128) * 8, &vS[cur ^ 1][(tid + i * 128) * 8]);
            }
        }

        // S^T[kl][ql] = sum_d K[kl][d] * Q[ql][d]; each kf read feeds BOTH sets
        f32x16 sT0, sT1;
#pragma unroll
        for (int i = 0; i < 16; ++i) { sT0[i] = 0.f; sT1[i] = 0.f; }
#pragma unroll
        for (int s = 0; s < 8; ++s) {
            bf16x8 kf = *(const bf16x8*)&kS[cur][c5 * DHEAD + (((2 * s + hi) ^ ksw) * 8)];
            sT0 = __builtin_amdgcn_mfma_f32_32x32x16_bf16(kf, qf0[s], sT0, 0, 0, 0);
            sT1 = __builtin_amdgcn_mfma_f32_32x32x16_bf16(kf, qf1[s], sT1, 0, 0, 0);
        }

        // fixed-max softmax fully in-register; pack pairs -> PV B-frags
        unsigned pw0[8], pw1[8];
#pragma unroll
        for (int i = 0; i < 8; ++i) {
            float a0 = exp2f(sT0[2 * i]);
            float b0 = exp2f(sT0[2 * i + 1]);
            float a1 = exp2f(sT1[2 * i]);
            float b1 = exp2f(sT1[2 * i + 1]);
            lp0 += a0 + b0;
            lp1 += a1 + b1;
            unsigned r0, r1;
            asm("v_cvt_pk_bf16_f32 %0, %1, %2" : "=v"(r0) : "v"(a0), "v"(b0));
            asm("v_cvt_pk_bf16_f32 %0, %1, %2" : "=v"(r1) : "v"(a1), "v"(b1));
            pw0[i] = r0;
            pw1[i] = r1;
        }
        bf16x8 p0a = __builtin_bit_cast(bf16x8, (u32x4){pw0[0], pw0[1], pw0[2], pw0[3]});
        bf16x8 p0b = __builtin_bit_cast(bf16x8, (u32x4){pw0[4], pw0[5], pw0[6], pw0[7]});
        bf16x8 p1a = __builtin_bit_cast(bf16x8, (u32x4){pw1[0], pw1[1], pw1[2], pw1[3]});
        bf16x8 p1b = __builtin_bit_cast(bf16x8, (u32x4){pw1[4], pw1[5], pw1[6], pw1[7]});

        // O[dv][ql] += V . P^T; each vf read feeds BOTH sets
#pragma unroll
        for (int t = 0; t < 4; ++t) {
            bf16x8 va = *(const bf16x8*)&vS[cur][(32 * t + c5) * BK + (((0 + hi) ^ vsw) * 8)];
            bf16x8 vb8 = *(const bf16x8*)&vS[cur][(32 * t + c5) * BK + (((2 + hi) ^ vsw) * 8)];
            acc0[t] = __builtin_amdgcn_mfma_f32_32x32x16_bf16(va,  p0a, acc0[t], 0, 0, 0);
            acc0[t] = __builtin_amdgcn_mfma_f32_32x32x16_bf16(vb8, p0b, acc0[t], 0, 0, 0);
            acc1[t] = __builtin_amdgcn_mfma_f32_32x32x16_bf16(va,  p1a, acc1[t], 0, 0, 0);
            acc1[t] = __builtin_amdgcn_mfma_f32_32x32x16_bf16(vb8, p1b, acc1[t], 0, 0, 0);
        }
    }

    // epilogue: per set, L[ql] = lp(hi=0) + lp(hi=1); normalize, gamma
    const float gm = gamma[0];
    {
        const float L0 = lp0 + __shfl_xor(lp0, 32);
        const float sc0 = gm / L0;
        const int ql = ql0 + c5;
#pragma unroll
        for (int t = 0; t < 4; ++t)
#pragma unroll
            for (int r = 0; r < 16; ++r) {
                int dvr = 32 * t + (r & 3) + 8 * (r >> 2) + 4 * hi;
                op[(size_t)dvr * SEQ + ql] = acc0[t][r] * sc0;
            }
    }
    {
        const float L1 = lp1 + __shfl_xor(lp1, 32);
        const float sc1 = gm / L1;
        const int ql = ql0 + 32 + c5;
#pragma unroll
        for (int t = 0; t < 4; ++t)
#pragma unroll
            for (int r = 0; r < 16; ++r) {
                int dvr = 32 * t + (r & 3) + 8 * (r >> 2) + 4 * hi;
                op[(size_t)dvr * SEQ + ql] = acc1[t][r] * sc1;
            }
    }
}

extern "C" void kernel_launch(void* const* d_in, const int* in_sizes, int n_in,
                              void* d_out, int out_size, void* d_ws, size_t ws_size,
                              hipStream_t stream) {
    (void)in_sizes; (void)n_in; (void)out_size; (void)ws_size;
    const float* q = (const float*)d_in[0];
    const float* k = (const float*)d_in[1];
    const float* v = (const float*)d_in[2];
    const float* g = (const float*)d_in[3];
    float* out = (float*)d_out;

    // ws: kT bf16 (16 MB) | vTiled bf16 (16 MB)
    const size_t PER_T = (size_t)NBH * SEQ * DHEAD;
    unsigned short* kws = (unsigned short*)d_ws;
    unsigned short* vws = kws + PER_T;

    cvt_kernel<<<dim3(1024 + 4096), dim3(256), 0, stream>>>(k, v, kws, vws);
    attn_main<<<dim3(512), dim3(128), 0, stream>>>(q, kws, vws, g, out);
}

// Round 3
// 237.326 us; speedup vs baseline: 1.0726x; 1.0726x over previous
//
#include <hip/hip_runtime.h>

#define SEQ 2048
#define DHEAD 128
#define BK 32
#define NBH 32
#define NTH 32   // K/V tiles per sequence half

typedef __attribute__((ext_vector_type(8))) short bf16x8;
typedef __attribute__((ext_vector_type(4))) short bf16x4;
typedef __attribute__((ext_vector_type(16))) float f32x16;
typedef __attribute__((ext_vector_type(4))) unsigned int u32x4;

__device__ __forceinline__ unsigned short f2bf(float f) {
    unsigned u = __builtin_bit_cast(unsigned, f);
    u += 0x7fffu + ((u >> 16) & 1u);
    return (unsigned short)(u >> 16);
}

__device__ __forceinline__ float fexp2(float x) {
    float r;
    asm("v_exp_f32 %0, %1" : "=v"(r) : "v"(x));   // native 2^x, schedulable
    return r;
}

__device__ __forceinline__ void gload16(const unsigned short* g, unsigned short* l) {
    __builtin_amdgcn_global_load_lds((const __attribute__((address_space(1))) void*)g,
                                     (__attribute__((address_space(3))) void*)l, 16, 0, 0);
}

// Fused prepass (unchanged from round 2 — layouts verified passing).
// Blocks 0..1023: K fp32 [bh*128+d][2048] -> bf16 [bh][l][128], 16B-chunk
// XOR-swizzled: phys = logical ^ ((l&7) ^ (((l>>3)&3)<<1)).
// Blocks 1024..5119: V fp32 -> bf16 [bh][kt][dv][32] with kl bits 2<->3
// swapped (PV B-frag register order), chunk-swizzled
// phys = logical ^ (((dv>>1)&3) ^ ((dv>>3)&3)).
__global__ __launch_bounds__(256)
void cvt_kernel(const float* __restrict__ kin, const float* __restrict__ vin,
                unsigned short* __restrict__ kout, unsigned short* __restrict__ vout) {
    const int tid = threadIdx.x;
    if (blockIdx.x < 1024) {
        __shared__ unsigned short tileT[DHEAD][66];   // [d][l]
        const int bh = blockIdx.x & 31;
        const int l0 = (blockIdx.x >> 5) * 64;
        const float* ip = kin + (size_t)bh * DHEAD * SEQ;
        unsigned short* opx = kout + ((size_t)bh * SEQ + l0) * DHEAD;
        const int l4 = (tid & 15) * 4;
        const int dq = tid >> 4;
        for (int pass = 0; pass < 8; ++pass) {
            int d = pass * 16 + dq;
            float4 f = *(const float4*)&ip[(size_t)d * SEQ + l0 + l4];
            unsigned lo = (unsigned)f2bf(f.x) | ((unsigned)f2bf(f.y) << 16);
            unsigned hi = (unsigned)f2bf(f.z) | ((unsigned)f2bf(f.w) << 16);
            *(unsigned*)&tileT[d][l4]     = lo;
            *(unsigned*)&tileT[d][l4 + 2] = hi;
        }
        __syncthreads();
        const int lw = tid >> 2;
        const int cw = tid & 3;
        const int ksw = (lw & 7) ^ (((lw >> 3) & 3) << 1);   // row = lw & 31 in-tile
        for (int j = 0; j < 4; ++j) {
            int pc = j * 4 + cw;           // phys chunk
            int lc = pc ^ ksw;             // logical chunk
            unsigned short tmp[8];
            for (int k2 = 0; k2 < 8; ++k2) tmp[k2] = tileT[lc * 8 + k2][lw];
            *(bf16x8*)&opx[(size_t)lw * DHEAD + pc * 8] = *(bf16x8*)tmp;
        }
    } else {
        size_t f = ((size_t)(blockIdx.x - 1024) * 256 + tid) * 8;
        int bh  = (int)(f >> 18);
        int rem = (int)(f & 262143);
        int kt  = rem >> 12;
        int r2  = rem & 4095;
        int dv  = r2 >> 5;
        int e0  = r2 & 31;
        const float* src = vin + ((size_t)bh * DHEAD + dv) * SEQ + kt * BK + e0;
        float4 a = *(const float4*)src;
        float4 b = *(const float4*)(src + 4);
        unsigned short p0[4] = {f2bf(a.x), f2bf(a.y), f2bf(a.z), f2bf(a.w)};
        unsigned short p1[4] = {f2bf(b.x), f2bf(b.y), f2bf(b.z), f2bf(b.w)};
        const int aa = e0 >> 4;
        const int bb = (e0 >> 3) & 1;
        const int w  = ((dv >> 1) & 3) ^ ((dv >> 3) & 3);
        size_t rowb = ((size_t)bh * (SEQ / BK) + kt) * (DHEAD * BK) + (size_t)dv * BK;
        *(bf16x4*)&vout[rowb + (size_t)(((2 * aa) ^ w) * 8 + 4 * bb)]     = *(bf16x4*)p0;
        *(bf16x4*)&vout[rowb + (size_t)(((2 * aa + 1) ^ w) * 8 + 4 * bb)] = *(bf16x4*)p1;
    }
}

// Seq-split 32x32x16 swapped-operand attention, nQ=2 (64 q/wave),
// 4 waves/block: waves {0,1} = kt 0..31, waves {2,3} = kt 32..63 on the same
// 128 queries. Restores 2 waves/SIMD (round 2's 1/SIMD was latency-bound)
// while keeping round 2's halved LDS-read-per-MFMA. Fixed-max softmax makes
// the half-combine a pure add (no rescale), done via LDS in the epilogue.
__global__ __launch_bounds__(256, 2)
void attn_main(const float* __restrict__ q,
               const unsigned short* __restrict__ kTg,
               const unsigned short* __restrict__ vW,
               const float* __restrict__ gamma,
               float* __restrict__ out) {
    // 64KB: [half][dbuf] x (K 8KB + V 8KB); reused as f32 scratch in epilogue
    __shared__ __attribute__((aligned(16))) unsigned short smem[32768];

    const int tid  = threadIdx.x;        // 0..255
    const int wv   = tid >> 6;           // 0..3
    const int lane = tid & 63;
    const int c5   = lane & 31;
    const int hi   = lane >> 5;
    const int qw   = wv & 1;             // query-set of this wave
    const int sh   = wv >> 1;            // sequence half of this wave
    const int th   = tid >> 7;           // half this thread STAGES
    const int t7   = tid & 127;

    const int bh  = blockIdx.x & 31;     // same-head blocks stride 32 -> same XCD
    const int qlb = blockIdx.x >> 5;     // 0..15
    const size_t base = (size_t)bh * SEQ * DHEAD;

    const float* qp = q + base;              // fp32 [d][2048]
    const unsigned short* kb = kTg + base;   // [l][128] swizzled
    const unsigned short* vb = vW + base;    // [kt][dv][32] permuted+swizzled
    float* op = out + base;                  // [dv][2048]

    const int ql0 = qlb * 128 + qw * 64;
    const float SCL = 0.08838834764831845f * 1.44269504088896340f; // 1/sqrt(128)*log2e

    // staging source base for the half this thread stages
    const unsigned short* kb_h = kb + (size_t)(th * NTH) * (BK * DHEAD);
    const unsigned short* vb_h = vb + (size_t)(th * NTH) * (DHEAD * BK);

#define KBUF(h, b) (&smem[((h) * 2 + (b)) * 8192])
#define VBUF(h, b) (&smem[((h) * 2 + (b)) * 8192 + 4096])

    // prime tile 0 of each half into buf 0 (DMA flies during Q-frag load)
#pragma unroll
    for (int j = 0; j < 4; ++j) {
        gload16(kb_h + (size_t)(t7 + j * 128) * 8, KBUF(th, 0) + (t7 + j * 128) * 8);
        gload16(vb_h + (size_t)(t7 + j * 128) * 8, VBUF(th, 0) + (t7 + j * 128) * 8);
    }

    // Q B-frags for both query sets: B[n=ql][k=hi*8+j], d = s*16 + hi*8 + j
    bf16x8 qf0[8], qf1[8];
#pragma unroll
    for (int s = 0; s < 8; ++s) {
        bf16x8 t0, t1;
#pragma unroll
        for (int j = 0; j < 8; ++j) {
            const size_t drow = (size_t)(s * 16 + hi * 8 + j) * SEQ;
            t0[j] = (short)f2bf(qp[drow + ql0 + c5] * SCL);
            t1[j] = (short)f2bf(qp[drow + ql0 + 32 + c5] * SCL);
        }
        qf0[s] = t0;
        qf1[s] = t1;
    }

    f32x16 acc0[4], acc1[4];
#pragma unroll
    for (int t = 0; t < 4; ++t)
#pragma unroll
        for (int i = 0; i < 16; ++i) { acc0[t][i] = 0.f; acc1[t][i] = 0.f; }
    float lp0 = 0.f, lp1 = 0.f;

    // LDS element offsets, precomputed once (statically indexed -> registers)
    const int ksw = (c5 & 7) ^ (((c5 >> 3) & 3) << 1);
    const int vsw = ((c5 >> 1) & 3) ^ ((c5 >> 3) & 3);
    int koff[8], voffa[4], voffb[4];
#pragma unroll
    for (int s = 0; s < 8; ++s) koff[s] = c5 * DHEAD + (((2 * s + hi) ^ ksw) * 8);
#pragma unroll
    for (int t = 0; t < 4; ++t) {
        voffa[t] = (32 * t + c5) * BK + (((0 + hi) ^ vsw) * 8);
        voffb[t] = (32 * t + c5) * BK + (((2 + hi) ^ vsw) * 8);
    }

    auto body = [&](int i, int cur) {
        __syncthreads();   // buf[cur] landed (prefetch flew during previous compute)

        if (i + 1 < NTH) {   // prefetch next tile of this thread's half
            const unsigned short* kg = kb_h + (size_t)(i + 1) * (BK * DHEAD);
            const unsigned short* vg = vb_h + (size_t)(i + 1) * (DHEAD * BK);
            unsigned short* kd = KBUF(th, cur ^ 1);
            unsigned short* vd = VBUF(th, cur ^ 1);
#pragma unroll
            for (int j = 0; j < 4; ++j) {
                gload16(kg + (size_t)(t7 + j * 128) * 8, kd + (t7 + j * 128) * 8);
                gload16(vg + (size_t)(t7 + j * 128) * 8, vd + (t7 + j * 128) * 8);
            }
        }

        const unsigned short* kT = KBUF(sh, cur);
        const unsigned short* vT = VBUF(sh, cur);

        // S^T[kl][ql] = sum_d K[kl][d] * Q[ql][d]; each kf feeds BOTH q-sets
        f32x16 sT0, sT1;
#pragma unroll
        for (int ii = 0; ii < 16; ++ii) { sT0[ii] = 0.f; sT1[ii] = 0.f; }
        __builtin_amdgcn_s_setprio(1);
#pragma unroll
        for (int s = 0; s < 8; ++s) {
            bf16x8 kf = *(const bf16x8*)&kT[koff[s]];
            sT0 = __builtin_amdgcn_mfma_f32_32x32x16_bf16(kf, qf0[s], sT0, 0, 0, 0);
            sT1 = __builtin_amdgcn_mfma_f32_32x32x16_bf16(kf, qf1[s], sT1, 0, 0, 0);
        }
        __builtin_amdgcn_s_setprio(0);

        // fixed-max softmax fully in-register; pack pairs -> PV B-frags
        unsigned pw0[8], pw1[8];
#pragma unroll
        for (int ii = 0; ii < 8; ++ii) {
            float a0 = fexp2(sT0[2 * ii]);
            float b0 = fexp2(sT0[2 * ii + 1]);
            float a1 = fexp2(sT1[2 * ii]);
            float b1 = fexp2(sT1[2 * ii + 1]);
            lp0 += a0 + b0;
            lp1 += a1 + b1;
            unsigned r0, r1;
            asm("v_cvt_pk_bf16_f32 %0, %1, %2" : "=v"(r0) : "v"(a0), "v"(b0));
            asm("v_cvt_pk_bf16_f32 %0, %1, %2" : "=v"(r1) : "v"(a1), "v"(b1));
            pw0[ii] = r0;
            pw1[ii] = r1;
        }
        bf16x8 p0a = __builtin_bit_cast(bf16x8, (u32x4){pw0[0], pw0[1], pw0[2], pw0[3]});
        bf16x8 p0b = __builtin_bit_cast(bf16x8, (u32x4){pw0[4], pw0[5], pw0[6], pw0[7]});
        bf16x8 p1a = __builtin_bit_cast(bf16x8, (u32x4){pw1[0], pw1[1], pw1[2], pw1[3]});
        bf16x8 p1b = __builtin_bit_cast(bf16x8, (u32x4){pw1[4], pw1[5], pw1[6], pw1[7]});

        // O[dv][ql] += V . P^T; each vf read feeds BOTH q-sets
        __builtin_amdgcn_s_setprio(1);
#pragma unroll
        for (int t = 0; t < 4; ++t) {
            bf16x8 va  = *(const bf16x8*)&vT[voffa[t]];
            bf16x8 vb8 = *(const bf16x8*)&vT[voffb[t]];
            acc0[t] = __builtin_amdgcn_mfma_f32_32x32x16_bf16(va,  p0a, acc0[t], 0, 0, 0);
            acc0[t] = __builtin_amdgcn_mfma_f32_32x32x16_bf16(vb8, p0b, acc0[t], 0, 0, 0);
            acc1[t] = __builtin_amdgcn_mfma_f32_32x32x16_bf16(va,  p1a, acc1[t], 0, 0, 0);
            acc1[t] = __builtin_amdgcn_mfma_f32_32x32x16_bf16(vb8, p1b, acc1[t], 0, 0, 0);
        }
        __builtin_amdgcn_s_setprio(0);
    };

    for (int it = 0; it < NTH; it += 2) {   // unroll x2: both buf address sets loop-invariant
        body(it, 0);
        body(it + 1, 1);
    }

    // ---- epilogue: combine the two sequence halves, normalize, store ----
    // Phase A: lanewise lp exchange between partner waves (wv ^ 2).
    float* lbuf = (float*)smem;   // 2KB, disjoint from iter-31's active buffers
    lbuf[(wv * 2 + 0) * 64 + lane] = lp0;
    lbuf[(wv * 2 + 1) * 64 + lane] = lp1;
    __syncthreads();
    const int pw = wv ^ 2;
    lp0 += lbuf[(pw * 2 + 0) * 64 + lane];
    lp1 += lbuf[(pw * 2 + 1) * 64 + lane];
    const float Lt0 = lp0 + __shfl_xor(lp0, 32);
    const float Lt1 = lp1 + __shfl_xor(lp1, 32);
    const float gm = gamma[0];
    const float sc0 = gm / Lt0;
    const float sc1 = gm / Lt1;
    __syncthreads();

    // Phase B: each wave ships the dv-half it does NOT own (sh=0 owns t=0,1).
    // abuf layout: (((wv*2+qs)*2 + j)*16 + r)*64 + lane  (64KB exactly)
    float* abuf = (float*)smem;
    if (sh == 0) {
#pragma unroll
        for (int r = 0; r < 16; ++r) {
            abuf[(((wv * 2 + 0) * 2 + 0) * 16 + r) * 64 + lane] = acc0[2][r];
            abuf[(((wv * 2 + 0) * 2 + 1) * 16 + r) * 64 + lane] = acc0[3][r];
            abuf[(((wv * 2 + 1) * 2 + 0) * 16 + r) * 64 + lane] = acc1[2][r];
            abuf[(((wv * 2 + 1) * 2 + 1) * 16 + r) * 64 + lane] = acc1[3][r];
        }
    } else {
#pragma unroll
        for (int r = 0; r < 16; ++r) {
            abuf[(((wv * 2 + 0) * 2 + 0) * 16 + r) * 64 + lane] = acc0[0][r];
            abuf[(((wv * 2 + 0) * 2 + 1) * 16 + r) * 64 + lane] = acc0[1][r];
            abuf[(((wv * 2 + 1) * 2 + 0) * 16 + r) * 64 + lane] = acc1[0][r];
            abuf[(((wv * 2 + 1) * 2 + 1) * 16 + r) * 64 + lane] = acc1[1][r];
        }
    }
    __syncthreads();

    if (sh == 0) {       // own t = 0,1  (dv 0..63)
#pragma unroll
        for (int r = 0; r < 16; ++r) {
            float v00 = acc0[0][r] + abuf[(((pw * 2 + 0) * 2 + 0) * 16 + r) * 64 + lane];
            float v01 = acc0[1][r] + abuf[(((pw * 2 + 0) * 2 + 1) * 16 + r) * 64 + lane];
            float v10 = acc1[0][r] + abuf[(((pw * 2 + 1) * 2 + 0) * 16 + r) * 64 + lane];
            float v11 = acc1[1][r] + abuf[(((pw * 2 + 1) * 2 + 1) * 16 + r) * 64 + lane];
            int dvr = (r & 3) + 8 * (r >> 2) + 4 * hi;
            op[(size_t)(dvr)      * SEQ + ql0 +      c5] = v00 * sc0;
            op[(size_t)(32 + dvr) * SEQ + ql0 +      c5] = v01 * sc0;
            op[(size_t)(dvr)      * SEQ + ql0 + 32 + c5] = v10 * sc1;
            op[(size_t)(32 + dvr) * SEQ + ql0 + 32 + c5] = v11 * sc1;
        }
    } else {             // own t = 2,3  (dv 64..127)
#pragma unroll
        for (int r = 0; r < 16; ++r) {
            float v00 = acc0[2][r] + abuf[(((pw * 2 + 0) * 2 + 0) * 16 + r) * 64 + lane];
            float v01 = acc0[3][r] + abuf[(((pw * 2 + 0) * 2 + 1) * 16 + r) * 64 + lane];
            float v10 = acc1[2][r] + abuf[(((pw * 2 + 1) * 2 + 0) * 16 + r) * 64 + lane];
            float v11 = acc1[3][r] + abuf[(((pw * 2 + 1) * 2 + 1) * 16 + r) * 64 + lane];
            int dvr = (r & 3) + 8 * (r >> 2) + 4 * hi;
            op[(size_t)(64 + dvr) * SEQ + ql0 +      c5] = v00 * sc0;
            op[(size_t)(96 + dvr) * SEQ + ql0 +      c5] = v01 * sc0;
            op[(size_t)(64 + dvr) * SEQ + ql0 + 32 + c5] = v10 * sc1;
            op[(size_t)(96 + dvr) * SEQ + ql0 + 32 + c5] = v11 * sc1;
        }
    }
#undef KBUF
#undef VBUF
}

extern "C" void kernel_launch(void* const* d_in, const int* in_sizes, int n_in,
                              void* d_out, int out_size, void* d_ws, size_t ws_size,
                              hipStream_t stream) {
    (void)in_sizes; (void)n_in; (void)out_size; (void)ws_size;
    const float* q = (const float*)d_in[0];
    const float* k = (const float*)d_in[1];
    const float* v = (const float*)d_in[2];
    const float* g = (const float*)d_in[3];
    float* out = (float*)d_out;

    // ws: kT bf16 (16 MB) | vTiled bf16 (16 MB)
    const size_t PER_T = (size_t)NBH * SEQ * DHEAD;
    unsigned short* kws = (unsigned short*)d_ws;
    unsigned short* vws = kws + PER_T;

    cvt_kernel<<<dim3(1024 + 4096), dim3(256), 0, stream>>>(k, v, kws, vws);
    attn_main<<<dim3(512), dim3(256), 0, stream>>>(q, kws, vws, g, out);
}

// Round 6
// 223.772 us; speedup vs baseline: 1.1376x; 1.0606x over previous
//
#include <hip/hip_runtime.h>

#define SEQ 2048
#define DHEAD 128
#define BK 32
#define NBH 32

typedef __attribute__((ext_vector_type(8))) short bf16x8;
typedef __attribute__((ext_vector_type(4))) short bf16x4;
typedef __attribute__((ext_vector_type(16))) float f32x16;
typedef __attribute__((ext_vector_type(4))) unsigned int u32x4;

__device__ __forceinline__ unsigned short f2bf(float f) {
    unsigned u = __builtin_bit_cast(unsigned, f);
    u += 0x7fffu + ((u >> 16) & 1u);
    return (unsigned short)(u >> 16);
}

__device__ __forceinline__ float fexp2(float x) {
    float r;
    asm("v_exp_f32 %0, %1" : "=v"(r) : "v"(x));   // native 2^x
    return r;
}

// Fused prepass -> FRAGMENT-MAJOR global layouts (no LDS staging in attn).
// K: kout[bh][kt][s][hi][c5][8] bf16, element = K[l = kt*32+c5][d = s*16+hi*8+j].
//    A fragment load in attn is then kout + tile*4096 + s*512 + lane*8: one
//    perfectly coalesced 16B/lane global_load_dwordx4 per frag.
// V: vout[bh][kt][u][a][hi][c5][8] bf16, element = V[dv = u*32+c5]
//    [kl = 16a + 8*(j>>2) + 4*hi + (j&3)]  (the kl bit2<->3 permutation that
//    matches the in-register P fragment order — verified in rounds 1-3).
__global__ __launch_bounds__(256)
void cvt_kernel(const float* __restrict__ kin, const float* __restrict__ vin,
                unsigned short* __restrict__ kout, unsigned short* __restrict__ vout) {
    const int tid = threadIdx.x;
    if (blockIdx.x < 1024) {
        __shared__ unsigned short tileT[DHEAD][66];   // [d][l-local]
        const int bh = blockIdx.x & 31;
        const int l0 = (blockIdx.x >> 5) * 64;        // 64 seq positions = 2 tiles
        const float* ip = kin + (size_t)bh * DHEAD * SEQ;
        const int l4 = (tid & 15) * 4;
        const int dq = tid >> 4;
        for (int pass = 0; pass < 8; ++pass) {
            int d = pass * 16 + dq;
            float4 f = *(const float4*)&ip[(size_t)d * SEQ + l0 + l4];
            unsigned lo = (unsigned)f2bf(f.x) | ((unsigned)f2bf(f.y) << 16);
            unsigned hi = (unsigned)f2bf(f.z) | ((unsigned)f2bf(f.w) << 16);
            *(unsigned*)&tileT[d][l4]     = lo;
            *(unsigned*)&tileT[d][l4 + 2] = hi;
        }
        __syncthreads();
        // 1024 fragment-chunks per block (2 kt x 8 s x 2 hi x 32 c5), 4/thread
        for (int m = 0; m < 4; ++m) {
            int chunk = m * 256 + tid;
            int c5  = chunk & 31;
            int hi  = (chunk >> 5) & 1;
            int s   = (chunk >> 6) & 7;
            int ktl = chunk >> 9;                     // 0..1
            unsigned short tmp[8];
#pragma unroll
            for (int j = 0; j < 8; ++j) tmp[j] = tileT[s * 16 + hi * 8 + j][ktl * 32 + c5];
            size_t gkt = (size_t)(l0 >> 5) + ktl;     // global tile 0..63
            size_t off = ((size_t)bh * 64 + gkt) * 4096 + (size_t)(((s * 2 + hi) * 32 + c5) * 8);
            *(bf16x8*)&kout[off] = *(bf16x8*)tmp;
        }
    } else {
        size_t f = ((size_t)(blockIdx.x - 1024) * 256 + tid) * 8;
        int bh  = (int)(f >> 18);
        int rem = (int)(f & 262143);
        int kt  = rem >> 12;
        int r2  = rem & 4095;
        int dv  = r2 >> 5;
        int e0  = r2 & 31;
        const float* src = vin + ((size_t)bh * DHEAD + dv) * SEQ + kt * BK + e0;
        float4 a = *(const float4*)src;
        float4 b = *(const float4*)(src + 4);
        unsigned short p0[4] = {f2bf(a.x), f2bf(a.y), f2bf(a.z), f2bf(a.w)};  // kl e0+0..3 (bit2=0 -> hi=0)
        unsigned short p1[4] = {f2bf(b.x), f2bf(b.y), f2bf(b.z), f2bf(b.w)};  // kl e0+4..7 (bit2=1 -> hi=1)
        // kl = 16*aa + 8*bb + 4*h + t  ->  frag coords a=aa, j = 4*bb + t, hi = h
        const int aa = e0 >> 4;
        const int bb = (e0 >> 3) & 1;
        const int u  = dv >> 5;
        const int cv = dv & 31;
        size_t tb = ((size_t)bh * 64 + kt) * 4096;
        size_t o0 = tb + (size_t)((((u * 2 + aa) * 2 + 0) * 32 + cv) * 8 + 4 * bb);
        size_t o1 = tb + (size_t)((((u * 2 + aa) * 2 + 1) * 32 + cv) * 8 + 4 * bb);
        *(bf16x4*)&vout[o0] = *(bf16x4*)p0;
        *(bf16x4*)&vout[o1] = *(bf16x4*)p1;
    }
}

// LDS-free attention. Waves split by (q-half x dv-half); each wave iterates
// the FULL sequence, loading K/V fragments straight from the fragment-major
// global layouts (coalesced 16B/lane). QK^T is duplicated across the dv-pair
// (MFMA has 4x headroom); each wave owns its (q,dv) outputs so there is no
// epilogue combine, no __shared__, no barriers, and no inter-wave races by
// construction. acc = 64 AGPR/wave; total regs ~210 < 256 -> 2 waves/SIMD,
// 2 blocks/CU: 8 independent waves hide global-load latency by TLP, and V
// loads issue before QK so their latency hides under compute.
__global__ __launch_bounds__(256, 2)
void attn_main(const float* __restrict__ q,
               const unsigned short* __restrict__ kF,
               const unsigned short* __restrict__ vF,
               const float* __restrict__ gamma,
               float* __restrict__ out) {
    const int tid  = threadIdx.x;
    const int wv   = tid >> 6;
    const int lane = tid & 63;
    const int c5   = lane & 31;
    const int hi   = lane >> 5;
    const int qh   = wv & 1;             // q 64-half
    const int dh   = wv >> 1;            // dv 64-half

    const int bh  = blockIdx.x & 31;     // same-head blocks stride 32 -> same XCD
    const int qlb = blockIdx.x >> 5;     // 0..15
    const size_t base = (size_t)bh * SEQ * DHEAD;   // == bh*64*4096

    const float* qp = q + base;              // fp32 [d][2048]
    const unsigned short* kb = kF + base;    // frag-major K
    const unsigned short* vb = vF + base;    // frag-major V
    float* op = out + base;                  // [dv][2048]

    const int ql0 = qlb * 128 + qh * 64;
    const float SCL = 0.08838834764831845f * 1.44269504088896340f; // 1/sqrt(128)*log2e

    // Q B-frags (one-time): B[n=ql][k=hi*8+j], d = s*16 + hi*8 + j
    bf16x8 qf0[8], qf1[8];
#pragma unroll
    for (int s = 0; s < 8; ++s) {
        bf16x8 t0, t1;
#pragma unroll
        for (int j = 0; j < 8; ++j) {
            const size_t drow = (size_t)(s * 16 + hi * 8 + j) * SEQ;
            t0[j] = (short)f2bf(qp[drow + ql0 + c5] * SCL);
            t1[j] = (short)f2bf(qp[drow + ql0 + 32 + c5] * SCL);
        }
        qf0[s] = t0;
        qf1[s] = t1;
    }

    f32x16 acc0[2], acc1[2];
#pragma unroll
    for (int t = 0; t < 2; ++t)
#pragma unroll
        for (int i = 0; i < 16; ++i) { acc0[t][i] = 0.f; acc1[t][i] = 0.f; }
    float lp0 = 0.f, lp1 = 0.f;

    const int ko = lane * 8;             // K frag: s*512 + lane*8
    int voff[4];                         // V frag (t2, a) for this dv-half
#pragma unroll
    for (int t2 = 0; t2 < 2; ++t2)
#pragma unroll
        for (int a = 0; a < 2; ++a)
            voff[t2 * 2 + a] = (((dh * 2 + t2) * 2 + a) * 2 + hi) * 256 + c5 * 8;

    for (int kt = 0; kt < SEQ / BK; ++kt) {
        const unsigned short* kT = kb + (size_t)kt * 4096;
        const unsigned short* vT = vb + (size_t)kt * 4096;

        // issue all K and V fragment loads up front; latency hides under QK
        bf16x8 kf[8], vf[4];
#pragma unroll
        for (int s = 0; s < 8; ++s) kf[s] = *(const bf16x8*)&kT[s * 512 + ko];
#pragma unroll
        for (int t = 0; t < 4; ++t) vf[t] = *(const bf16x8*)&vT[voff[t]];

        // S^T[kl][ql] = sum_d K[kl][d] * Q[ql][d]
        f32x16 sT0, sT1;
#pragma unroll
        for (int ii = 0; ii < 16; ++ii) { sT0[ii] = 0.f; sT1[ii] = 0.f; }
        __builtin_amdgcn_s_setprio(1);
#pragma unroll
        for (int s = 0; s < 8; ++s) {
            sT0 = __builtin_amdgcn_mfma_f32_32x32x16_bf16(kf[s], qf0[s], sT0, 0, 0, 0);
            sT1 = __builtin_amdgcn_mfma_f32_32x32x16_bf16(kf[s], qf1[s], sT1, 0, 0, 0);
        }
        __builtin_amdgcn_s_setprio(0);

        // fixed-max softmax in-register; pack pairs -> PV B-frags
        unsigned pw0[8], pw1[8];
#pragma unroll
        for (int ii = 0; ii < 8; ++ii) {
            float a0 = fexp2(sT0[2 * ii]);
            float b0 = fexp2(sT0[2 * ii + 1]);
            float a1 = fexp2(sT1[2 * ii]);
            float b1 = fexp2(sT1[2 * ii + 1]);
            lp0 += a0 + b0;
            lp1 += a1 + b1;
            unsigned r0, r1;
            asm("v_cvt_pk_bf16_f32 %0, %1, %2" : "=v"(r0) : "v"(a0), "v"(b0));
            asm("v_cvt_pk_bf16_f32 %0, %1, %2" : "=v"(r1) : "v"(a1), "v"(b1));
            pw0[ii] = r0;
            pw1[ii] = r1;
        }
        bf16x8 p0a = __builtin_bit_cast(bf16x8, (u32x4){pw0[0], pw0[1], pw0[2], pw0[3]});
        bf16x8 p0b = __builtin_bit_cast(bf16x8, (u32x4){pw0[4], pw0[5], pw0[6], pw0[7]});
        bf16x8 p1a = __builtin_bit_cast(bf16x8, (u32x4){pw1[0], pw1[1], pw1[2], pw1[3]});
        bf16x8 p1b = __builtin_bit_cast(bf16x8, (u32x4){pw1[4], pw1[5], pw1[6], pw1[7]});

        // O[dv][ql] += V . P^T (this wave's dv-half only)
        __builtin_amdgcn_s_setprio(1);
#pragma unroll
        for (int t2 = 0; t2 < 2; ++t2) {
            acc0[t2] = __builtin_amdgcn_mfma_f32_32x32x16_bf16(vf[t2 * 2],     p0a, acc0[t2], 0, 0, 0);
            acc0[t2] = __builtin_amdgcn_mfma_f32_32x32x16_bf16(vf[t2 * 2 + 1], p0b, acc0[t2], 0, 0, 0);
            acc1[t2] = __builtin_amdgcn_mfma_f32_32x32x16_bf16(vf[t2 * 2],     p1a, acc1[t2], 0, 0, 0);
            acc1[t2] = __builtin_amdgcn_mfma_f32_32x32x16_bf16(vf[t2 * 2 + 1], p1b, acc1[t2], 0, 0, 0);
        }
        __builtin_amdgcn_s_setprio(0);
    }

    // epilogue: L[ql] = lp(hi=0) + lp(hi=1) over the FULL sequence (wave-local)
    const float gm = gamma[0];
    const float L0 = lp0 + __shfl_xor(lp0, 32);
    const float L1 = lp1 + __shfl_xor(lp1, 32);
    const float sc0 = gm / L0;
    const float sc1 = gm / L1;
#pragma unroll
    for (int t2 = 0; t2 < 2; ++t2)
#pragma unroll
        for (int r = 0; r < 16; ++r) {
            int dvr = 32 * (dh * 2 + t2) + (r & 3) + 8 * (r >> 2) + 4 * hi;
            op[(size_t)dvr * SEQ + ql0 + c5]      = acc0[t2][r] * sc0;
            op[(size_t)dvr * SEQ + ql0 + 32 + c5] = acc1[t2][r] * sc1;
        }
}

extern "C" void kernel_launch(void* const* d_in, const int* in_sizes, int n_in,
                              void* d_out, int out_size, void* d_ws, size_t ws_size,
                              hipStream_t stream) {
    (void)in_sizes; (void)n_in; (void)out_size; (void)ws_size;
    const float* q = (const float*)d_in[0];
    const float* k = (const float*)d_in[1];
    const float* v = (const float*)d_in[2];
    const float* g = (const float*)d_in[3];
    float* out = (float*)d_out;

    // ws: K frags bf16 (16 MB) | V frags bf16 (16 MB)
    const size_t PER_T = (size_t)NBH * SEQ * DHEAD;
    unsigned short* kws = (unsigned short*)d_ws;
    unsigned short* vws = kws + PER_T;

    cvt_kernel<<<dim3(1024 + 4096), dim3(256), 0, stream>>>(k, v, kws, vws);
    attn_main<<<dim3(512), dim3(256), 0, stream>>>(q, kws, vws, g, out);
}